// Round 3
// baseline (436.333 us; speedup 1.0000x reference)
//
#include <hip/hip_runtime.h>
#include <cstdint>
#include <cstddef>

// Problem constants (from reference setup_inputs)
constexpr int P  = 200000;   // points
constexpr int C  = 256;      // clicks
constexpr int NC = 200;      // classes
#define DICE_TH 0.4f
#define CLS_TH  0.5f
#define LN_EPS  1e-5f

// gram split-K config: KC * NCHUNK == P, KC % 32 == 0
constexpr int KC = 800;
constexpr int NCHUNK = 250;
constexpr int NSTEP = KC / 32;   // 25

// workspace byte offsets
constexpr size_t WS_G       = 0;        // 256*256*4 = 262144
constexpr size_t WS_S       = 262144;   // 256*4
constexpr size_t WS_PROW    = 263168;   // 256*200*4 = 204800
constexpr size_t WS_PT      = 467968;   // 200*256*4 = 204800
constexpr size_t WS_COND    = 672768;   // 256*4*8 = 8192
constexpr size_t WS_MSTART  = 680960;   // 257*4
constexpr size_t WS_MEMBERS = 682240;   // 256*4
constexpr size_t WS_PART    = 1048576;  // partial G tiles (big-ws path)
constexpr size_t PART_BYTES = (size_t)NCHUNK * 65536 * 4;  // 65.536 MB

typedef float floatx4 __attribute__((ext_vector_type(4)));
typedef float floatx16 __attribute__((ext_vector_type(16)));
typedef __bf16 bf16x4 __attribute__((ext_vector_type(4)));
typedef __bf16 bf16x8 __attribute__((ext_vector_type(8)));
typedef unsigned short ushort4v __attribute__((ext_vector_type(4)));
typedef unsigned short ushort8 __attribute__((ext_vector_type(8)));

// ---------------------------------------------------------------------------
// Kernel 1: full G = M^T M via bf16 MFMA, split-K over 250 chunks.
// 512 threads / 8 waves (4 row-strips x 2 col-strips), each block stages the
// FULL 256-col row-slab once per 32-k step -> M is read from HBM exactly once
// across the whole dispatch. Column sums s fused (every block adds its
// k-partial). Epilogue: big-ws -> per-chunk 256x256 partial tile (plain
// stores, summed inside cond); small-ws fallback -> atomicAdd into G.
// LDS: single [col][k] bf16 buffer, LDA=40, even-XOR swizzle
// (write pos kq^(((col>>2)&3)<<1); read xa=((mrow>>2)&3)<<1).
// ---------------------------------------------------------------------------
constexpr int LDA = 40;

__global__ __launch_bounds__(512, 2) void gram_mfma_kernel(
    const float* __restrict__ M, float* __restrict__ G, float* __restrict__ s,
    float* __restrict__ part) {
  __shared__ unsigned short Abf[256 * LDA];
  __shared__ float scol[256];

  const int tid = threadIdx.x;
  const int wv = tid >> 6, lane = tid & 63;
  const int wr = wv >> 1, wc = wv & 1;      // wave -> 64row x 128col sub-tile
  const int g  = tid & 63;                  // column group (4 cols, 0..63)
  const int kq = tid >> 6;                  // k-quad in [0,8)
  const int chunk = blockIdx.x;
  const int k0 = chunk * KC;

  if (tid < 256) scol[tid] = 0.f;

  floatx16 acc[8];
#pragma unroll
  for (int t = 0; t < 8; ++t)
#pragma unroll
    for (int r = 0; r < 16; ++r) acc[t][r] = 0.f;
  float ss[4] = {0.f, 0.f, 0.f, 0.f};

  const int mrow = lane & 31;
  const int kgrp = (lane >> 5) * 8;
  const int xa = ((mrow >> 2) & 3) << 1;         // read-side XOR
  const int wbase = (kq ^ ((g & 3) << 1)) << 2;  // swizzled write offset

  const float* baseA = M + 4 * g;

#define LOADS(dst, step_)                                                    \
  {                                                                          \
    const float* src_ = baseA + (size_t)(k0 + (step_) * 32 + 4 * kq) * 256;  \
    dst[0] = *reinterpret_cast<const floatx4*>(src_);                        \
    dst[1] = *reinterpret_cast<const floatx4*>(src_ + 256);                  \
    dst[2] = *reinterpret_cast<const floatx4*>(src_ + 512);                  \
    dst[3] = *reinterpret_cast<const floatx4*>(src_ + 768);                  \
  }

#define STAGE(r_)                                                            \
  {                                                                          \
    ss[0] += r_[0][0] + r_[1][0] + r_[2][0] + r_[3][0];                      \
    ss[1] += r_[0][1] + r_[1][1] + r_[2][1] + r_[3][1];                      \
    ss[2] += r_[0][2] + r_[1][2] + r_[2][2] + r_[3][2];                      \
    ss[3] += r_[0][3] + r_[1][3] + r_[2][3] + r_[3][3];                      \
    _Pragma("unroll") for (int cc = 0; cc < 4; ++cc) {                       \
      floatx4 f = {r_[0][cc], r_[1][cc], r_[2][cc], r_[3][cc]};              \
      bf16x4 b = __builtin_convertvector(f, bf16x4);                         \
      *reinterpret_cast<ushort4v*>(&Abf[(4 * g + cc) * LDA + wbase]) =       \
          __builtin_bit_cast(ushort4v, b);                                   \
    }                                                                        \
  }

#define MFMA_STEP()                                                          \
  {                                                                          \
    _Pragma("unroll") for (int sub = 0; sub < 2; ++sub) {                    \
      const int ko = sub * 16 + kgrp;                                        \
      const int koff = (((ko >> 2) ^ xa) << 2);                              \
      bf16x8 av0 = __builtin_bit_cast(                                       \
          bf16x8, *reinterpret_cast<const ushort8*>(                         \
                      &Abf[(64 * wr + mrow) * LDA + koff]));                 \
      bf16x8 av1 = __builtin_bit_cast(                                       \
          bf16x8, *reinterpret_cast<const ushort8*>(                         \
                      &Abf[(64 * wr + 32 + mrow) * LDA + koff]));            \
      _Pragma("unroll") for (int bj = 0; bj < 4; ++bj) {                     \
        bf16x8 bv = __builtin_bit_cast(                                      \
            bf16x8, *reinterpret_cast<const ushort8*>(                       \
                        &Abf[(128 * wc + 32 * bj + mrow) * LDA + koff]));    \
        acc[bj] = __builtin_amdgcn_mfma_f32_32x32x16_bf16(av0, bv, acc[bj], 0, 0, 0); \
        acc[4 + bj] = __builtin_amdgcn_mfma_f32_32x32x16_bf16(av1, bv, acc[4 + bj], 0, 0, 0); \
      }                                                                      \
    }                                                                        \
  }

  floatx4 a0[4], a1[4];
  LOADS(a0, 0);

  for (int sp = 0; sp < NSTEP - 1; sp += 2) {
    STAGE(a0);
    __syncthreads();
    LOADS(a1, sp + 1);           // T14: in flight under MFMA
    MFMA_STEP();
    __syncthreads();

    STAGE(a1);
    __syncthreads();
    LOADS(a0, sp + 2);           // sp+2 <= NSTEP-1 since loop bound
    MFMA_STEP();
    __syncthreads();
  }
  // tail step (NSTEP odd): a0 holds step NSTEP-1
  STAGE(a0);
  __syncthreads();
  MFMA_STEP();
  __syncthreads();
#undef LOADS
#undef STAGE
#undef MFMA_STEP

  // epilogue: C/D layout col=lane&31, row=(r&3)+8*(r>>2)+4*(lane>>5)
  if (part != nullptr) {
    float* Pp = part + (size_t)chunk * 65536;
#pragma unroll
    for (int ai = 0; ai < 2; ++ai)
#pragma unroll
      for (int bj = 0; bj < 4; ++bj)
#pragma unroll
        for (int r = 0; r < 16; ++r) {
          const int lr = 64 * wr + 32 * ai + (r & 3) + 8 * (r >> 2) + 4 * (lane >> 5);
          const int lc = 128 * wc + 32 * bj + (lane & 31);
          Pp[lr * 256 + lc] = acc[ai * 4 + bj][r];
        }
  } else {
#pragma unroll
    for (int ai = 0; ai < 2; ++ai)
#pragma unroll
      for (int bj = 0; bj < 4; ++bj)
#pragma unroll
        for (int r = 0; r < 16; ++r) {
          const int gr = 64 * wr + 32 * ai + (r & 3) + 8 * (r >> 2) + 4 * (lane >> 5);
          const int gc = 128 * wc + 32 * bj + (lane & 31);
          atomicAdd(&G[(size_t)gr * 256 + gc], acc[ai * 4 + bj][r]);
        }
  }
  // column-sum partials: 8 k-quads share scol[4g+cc]
#pragma unroll
  for (int cc = 0; cc < 4; ++cc) atomicAdd(&scol[4 * g + cc], ss[cc]);
  __syncthreads();
  if (tid < 256) atomicAdd(&s[tid], scol[tid]);
}

// ---------------------------------------------------------------------------
// Kernel 2: layernorm of cls_logits -> p (row-major) and pT (transposed)
// ---------------------------------------------------------------------------
__global__ __launch_bounds__(64) void ln_kernel(const float* __restrict__ cls,
                                                float* __restrict__ p_row,
                                                float* __restrict__ pT) {
  const int c = blockIdx.x;
  const int t = threadIdx.x;
  const float* x = cls + (size_t)c * NC;
  float v0 = x[t];
  float v1 = x[t + 64];
  float v2 = (t < 72) ? x[t + 128] : 0.f;

  float sum = v0 + v1 + v2;
#pragma unroll
  for (int o = 32; o > 0; o >>= 1) sum += __shfl_xor(sum, o);
  const float mu = sum / (float)NC;

  float d0 = v0 - mu, d1 = v1 - mu, d2 = (t < 72) ? (v2 - mu) : 0.f;
  float sq = d0 * d0 + d1 * d1 + d2 * d2;
#pragma unroll
  for (int o = 32; o > 0; o >>= 1) sq += __shfl_xor(sq, o);
  const float var = sq / (float)NC;
  const float inv = 1.0f / sqrtf(var + LN_EPS);

  float p0 = d0 * inv, p1 = d1 * inv, p2 = d2 * inv;
  p_row[(size_t)c * NC + t] = p0;
  p_row[(size_t)c * NC + t + 64] = p1;
  pT[(size_t)t * C + c] = p0;
  pT[(size_t)(t + 64) * C + c] = p1;
  if (t < 72) {
    p_row[(size_t)c * NC + t + 128] = p2;
    pT[(size_t)(t + 128) * C + c] = p2;
  }
}

// ---------------------------------------------------------------------------
// Kernel 3: cond[i][j] = (dice > 0.4) && (sim > 0.5), packed 4x u64 per row.
// Big-ws path: sums the 250 per-chunk partial G tiles inline (L3-resident).
// Small-ws path: reads the atomically-accumulated full G.
// ---------------------------------------------------------------------------
__global__ __launch_bounds__(256) void cond_kernel(
    const float* __restrict__ G, const float* __restrict__ part,
    const float* __restrict__ s, const float* __restrict__ p_row,
    const float* __restrict__ pT, unsigned long long* __restrict__ condW) {
  __shared__ float pi[NC];
  const int i = blockIdx.x;
  const int j = threadIdx.x;
  if (j < NC) pi[j] = p_row[(size_t)i * NC + j];
  __syncthreads();

  float gsum;
  if (part != nullptr) {
    const float* src = part + (size_t)i * 256 + j;
    float s0 = 0.f, s1 = 0.f, s2 = 0.f, s3 = 0.f, s4 = 0.f;
#pragma unroll 1
    for (int ch = 0; ch < NCHUNK; ch += 5) {
      s0 += src[(size_t)(ch + 0) * 65536];
      s1 += src[(size_t)(ch + 1) * 65536];
      s2 += src[(size_t)(ch + 2) * 65536];
      s3 += src[(size_t)(ch + 3) * 65536];
      s4 += src[(size_t)(ch + 4) * 65536];
    }
    gsum = ((s0 + s1) + (s2 + s3)) + s4;
  } else {
    gsum = G[(size_t)i * C + j];
  }

  const float si = s[i];
  const float sj = s[j];
  const float dice = 2.f * gsum / (si + sj);

  float acc = 0.f;
#pragma unroll 8
  for (int k = 0; k < NC; ++k) acc = fmaf(pi[k], pT[(size_t)k * C + j], acc);

  const bool cnd = (dice > DICE_TH) && (acc > CLS_TH);
  unsigned long long m = __ballot(cnd);
  if ((j & 63) == 0) condW[i * 4 + (j >> 6)] = m;
}

// ---------------------------------------------------------------------------
// Kernel 4: sequential greedy scan (exact reference semantics), single wave.
// ---------------------------------------------------------------------------
__global__ __launch_bounds__(64) void scan_kernel(
    const unsigned long long* __restrict__ condW,
    float* __restrict__ out_labels, float* __restrict__ out_valid,
    int* __restrict__ mstart, int* __restrict__ members) {
  __shared__ unsigned long long cS[C * 4];
  __shared__ int cnt[C];
  __shared__ int ms[C + 1];
  const int t = threadIdx.x;

  for (int idx = t; idx < C * 4; idx += 64) cS[idx] = condW[idx];
  for (int idx = t; idx < C; idx += 64) cnt[idx] = 0;
  __syncthreads();

  unsigned long long asg[4] = {0ull, 0ull, 0ull, 0ull};
  int lab[4] = {-1, -1, -1, -1};   // lab[w] is label of column w*64 + t

#pragma unroll
  for (int w = 0; w < 4; ++w) {
    for (int b = 0; b < 64; ++b) {
      const int i = w * 64 + b;
      if (!((asg[w] >> b) & 1ull)) {   // leader i: take unassigned matches
#pragma unroll
        for (int w2 = 0; w2 < 4; ++w2) {
          unsigned long long tk = cS[i * 4 + w2] & ~asg[w2];
          asg[w2] |= tk;
          if ((tk >> t) & 1ull) lab[w2] = i;
        }
      }
    }
  }

  // counts per leader
#pragma unroll
  for (int w = 0; w < 4; ++w)
    if (lab[w] >= 0) atomicAdd(&cnt[lab[w]], 1);
  __syncthreads();

  if (t == 0) {
    ms[0] = 0;
    for (int c2 = 0; c2 < C; ++c2) ms[c2 + 1] = ms[c2] + cnt[c2];
  }
  __syncthreads();
  for (int idx = t; idx < C; idx += 64) cnt[idx] = ms[idx];
  __syncthreads();
#pragma unroll
  for (int w = 0; w < 4; ++w) {
    if (lab[w] >= 0) {
      int pos = atomicAdd(&cnt[lab[w]], 1);
      members[pos] = w * 64 + t;
    }
  }
#pragma unroll
  for (int w = 0; w < 4; ++w) {
    const int col = w * 64 + t;
    out_labels[col] = (float)lab[w];
    out_valid[col] = (ms[col + 1] > ms[col]) ? 1.0f : 0.0f;
  }
  for (int idx = t; idx < C + 1; idx += 64) mstart[idx] = ms[idx];
}

// ---------------------------------------------------------------------------
// Kernel 5: new_masks[p][c] = valid(c) ? max over members of M[p][j] : 0
// 16 rows per block (fewer blocks -> less metadata re-read / barrier count).
// ---------------------------------------------------------------------------
constexpr int MROWS = 16;

__global__ __launch_bounds__(256) void merge_masks_kernel(
    const float* __restrict__ M, const int* __restrict__ mstart,
    const int* __restrict__ members, float* __restrict__ out_masks) {
  __shared__ float rows[MROWS * 256];
  __shared__ int msS[C + 1];
  __shared__ int memS[C];
  const int tid = threadIdx.x;
  const size_t p0 = (size_t)blockIdx.x * MROWS;

  msS[tid] = mstart[tid];
  if (tid == 0) msS[C] = mstart[C];
  memS[tid] = members[tid];

  const float4* src = reinterpret_cast<const float4*>(M + p0 * 256);
#pragma unroll
  for (int it = 0; it < MROWS / 4; ++it)
    reinterpret_cast<float4*>(rows)[it * 256 + tid] = src[it * 256 + tid];
  __syncthreads();

  const int st = msS[tid], en = msS[tid + 1];
  float mx[MROWS];
  if (en > st) {
    const int m0 = memS[st];
#pragma unroll
    for (int r = 0; r < MROWS; ++r) mx[r] = rows[r * 256 + m0];
    for (int k = st + 1; k < en; ++k) {
      const int mm = memS[k];
#pragma unroll
      for (int r = 0; r < MROWS; ++r) mx[r] = fmaxf(mx[r], rows[r * 256 + mm]);
    }
  } else {
#pragma unroll
    for (int r = 0; r < MROWS; ++r) mx[r] = 0.f;
  }
  __syncthreads();                 // reuse rows as output staging
#pragma unroll
  for (int r = 0; r < MROWS; ++r) rows[r * 256 + tid] = mx[r];
  __syncthreads();

  const int r2 = tid >> 6;
  const int cg = (tid & 63) << 2;
#pragma unroll
  for (int pass = 0; pass < MROWS / 4; ++pass) {
    const int rr = pass * 4 + r2;
    floatx4 v = *reinterpret_cast<const floatx4*>(&rows[rr * 256 + cg]);
    __builtin_nontemporal_store(
        v, reinterpret_cast<floatx4*>(&out_masks[(p0 + rr) * 256 + cg]));
  }
}

// ---------------------------------------------------------------------------
// Kernel 6: new_cls[c][k] = valid(c) ? max over members of cls[j][k] : 0
// ---------------------------------------------------------------------------
__global__ __launch_bounds__(256) void merge_cls_kernel(
    const float* __restrict__ cls, const int* __restrict__ mstart,
    const int* __restrict__ members, float* __restrict__ out_cls) {
  __shared__ int se[2];
  const int c = blockIdx.x;
  const int t = threadIdx.x;
  if (t < 2) se[t] = mstart[c + t];
  __syncthreads();
  const int st = se[0], en = se[1];
  if (t < NC) {
    float mx = 0.f;
    if (en > st) {
      mx = cls[(size_t)members[st] * NC + t];
      for (int k = st + 1; k < en; ++k)
        mx = fmaxf(mx, cls[(size_t)members[k] * NC + t]);
    }
    out_cls[(size_t)c * NC + t] = mx;
  }
}

// ---------------------------------------------------------------------------
extern "C" void kernel_launch(void* const* d_in, const int* in_sizes, int n_in,
                              void* d_out, int out_size, void* d_ws,
                              size_t ws_size, hipStream_t stream) {
  const float* M = (const float*)d_in[0];    // [P, C] fp32
  const float* cls = (const float*)d_in[1];  // [C, NC] fp32

  float* out = (float*)d_out;
  char* ws = (char*)d_ws;
  float* G = (float*)(ws + WS_G);
  float* s = (float*)(ws + WS_S);
  float* p_row = (float*)(ws + WS_PROW);
  float* pT = (float*)(ws + WS_PT);
  unsigned long long* condW = (unsigned long long*)(ws + WS_COND);
  int* mstart = (int*)(ws + WS_MSTART);
  int* members = (int*)(ws + WS_MEMBERS);

  float* out_labels = out;
  float* out_valid = out + 256;
  float* out_masks = out + 512;
  float* out_cls = out + 512 + (size_t)P * 256;

  const bool bigws = ws_size >= WS_PART + PART_BYTES;
  float* part = bigws ? (float*)(ws + WS_PART) : nullptr;

  if (bigws) {
    hipMemsetAsync(ws + WS_S, 0, 1024, stream);       // s only
  } else {
    hipMemsetAsync(ws, 0, WS_S + 1024, stream);       // G + s (atomic path)
  }

  gram_mfma_kernel<<<NCHUNK, 512, 0, stream>>>(M, G, s, part);
  ln_kernel<<<C, 64, 0, stream>>>(cls, p_row, pT);
  cond_kernel<<<C, 256, 0, stream>>>(G, part, s, p_row, pT, condW);
  scan_kernel<<<1, 64, 0, stream>>>(condW, out_labels, out_valid, mstart,
                                    members);
  merge_masks_kernel<<<P / MROWS, 256, 0, stream>>>(M, mstart, members,
                                                    out_masks);
  merge_cls_kernel<<<C, 256, 0, stream>>>(cls, mstart, members, out_cls);
}